// Round 12
// baseline (133.311 us; speedup 1.0000x reference)
//
#include <hip/hip_runtime.h>
#include <hip/hip_bf16.h>
#include <math.h>

typedef __attribute__((ext_vector_type(4))) float f32x4;
typedef __attribute__((ext_vector_type(16))) float f32x16;
typedef __attribute__((ext_vector_type(8))) __bf16 bf16x8;
typedef __attribute__((ext_vector_type(4))) __bf16 bf16x4;
typedef __attribute__((ext_vector_type(4))) unsigned int u32x4;
typedef __attribute__((ext_vector_type(2))) unsigned int u32x2;

#define DEVI __device__ __forceinline__

DEVI f32x4 mfma16(bf16x8 a, bf16x8 b, f32x4 c) {
  return __builtin_amdgcn_mfma_f32_16x16x32_bf16(a, b, c, 0, 0, 0);
}
DEVI f32x16 mfma32(bf16x8 a, bf16x8 b, f32x16 c) {
  return __builtin_amdgcn_mfma_f32_32x32x16_bf16(a, b, c, 0, 0, 0);
}

// async global->LDS, 16B per lane; LDS dest = wave-uniform base + lane*16
DEVI void gload16(const void* g, void* l) {
  __builtin_amdgcn_global_load_lds(
      (const __attribute__((address_space(1))) void*)g,
      (__attribute__((address_space(3))) void*)l, 16, 0, 0);
}

DEVI float exp2a(float x) {  // single v_exp_f32 (exp2); inputs are log2-domain
  float r;
  asm("v_exp_f32 %0, %1" : "=v"(r) : "v"(x));
  return r;
}
DEVI unsigned cvtpk(float lo, float hi) {  // u32 = {bf16(lo), bf16(hi)}
  unsigned r;
  asm("v_cvt_pk_bf16_f32 %0, %1, %2" : "=v"(r) : "v"(lo), "v"(hi));
  return r;
}

#define LOG2E 1.4426950408889634f
#define QSCALE 0.18033688011110793f  /* 0.125 * log2(e) */
#define FIXMAX 8.0f  /* fixed softmax shift: S<<8 always; ratio O/lsum exact */

// ---------------- fused prep: x->bf16, W transposes, bias table ----------------
__global__ __launch_bounds__(256) void prep_k(
    const float* __restrict__ x, const float* __restrict__ W_attn,
    const float* __restrict__ W_proj, const float* __restrict__ bt,
    __bf16* __restrict__ xb, __bf16* __restrict__ WaT,
    __bf16* __restrict__ WpT, float* __restrict__ tbl) {
  __shared__ float tile[32][33];
  int bid = blockIdx.x;
  const int t = threadIdx.x;
  if (bid < 4096) {
    int i = (bid * 256 + t) * 4;
    float4 v = *(const float4*)&x[i];
    bf16x4 o = {(__bf16)v.x, (__bf16)v.y, (__bf16)v.z, (__bf16)v.w};
    *(bf16x4*)&xb[i] = o;
    return;
  }
  bid -= 4096;
  if (bid < 4096) {
    const float* in;
    __bf16* out;
    int Cc, bx, by;
    if (bid < 3072) {
      in = W_attn; out = WaT; Cc = 3072; bx = bid % 96; by = bid / 96;
    } else {
      int b2 = bid - 3072;
      in = W_proj; out = WpT; Cc = 1024; bx = b2 % 32; by = b2 / 32;
    }
    const int R = 1024;
    int tx = t & 31, ty = t >> 5;
    int xcol = bx * 32 + tx;
    for (int r = ty; r < 32; r += 8)
      tile[r][tx] = in[(size_t)(by * 32 + r) * Cc + xcol];
    __syncthreads();
    int xo = by * 32 + tx;
    for (int r = ty; r < 32; r += 8)
      out[(size_t)(bx * 32 + r) * R + xo] = (__bf16)tile[tx][r];
    return;
  }
  bid -= 4096;
  int idx = bid * 256 + t;  // h*2048 + rp
  int h = idx >> 11, rp = idx & 2047;
  int bucket;
  if (rp < 16) {
    bucket = rp;
  } else {
    float v = (logf((float)rp * 0.0625f) / 2.0794415416798357f) * 16.0f;
    bucket = 16 + (int)v;
    if (bucket > 31) bucket = 31;
  }
  tbl[idx] = bt[bucket * 16 + h] * LOG2E;
}

// ------- QKV GEMM: 256x256 8-phase template (m201-style), BK=64 -------
// 512 thr = 8 waves (2M x 4N), per-wave C = 128x64 (acc[8][4]).
// LDS 128KB: {A,B} x 2dbuf x 2half x [128][64] bf16, st_16x32 swizzle
// (byte ^= ((byte>>9)&1)<<5; for frag reads = kk ^ (rA&4 ? 32 : 0)).
// Staging: all 8 gload16 of tile kt+1 at phase 0 (after prior tile's last
// barrier -> write-safe); single vmcnt(0) at end of phase 3 (~600cy lead).
// Epilogue scatters q*QSCALE [B,H,T,D], k [B,H,T,D], vT [B,H,D,T].
__global__ __launch_bounds__(512, 2) void gemm_qkv(
    const __bf16* __restrict__ A, const __bf16* __restrict__ BT,
    const float* __restrict__ bias,
    __bf16* __restrict__ qb, __bf16* __restrict__ kb, __bf16* __restrict__ vtb) {
  __shared__ __align__(16) char lAm[65536];
  __shared__ __align__(16) char lBm[65536];
  const int t = threadIdx.x, w = t >> 6, lane = t & 63;
  const int wm = w >> 2, wn = w & 3;
  const int m0 = blockIdx.x * 256, n0 = blockIdx.y * 256;
  const int rA = lane & 15;
  const int aoff = rA * 128 + (((lane >> 4) * 16) ^ ((rA & 4) ? 32 : 0));
  const int bro = (wn & 1) * 8192;   // B row-base within half (bytes)

  // staging decode: thread's 16B chunk r -> (row, col) via inverse swizzle
  int srw[2], scl[2];
#pragma unroll
  for (int r = 0; r < 2; ++r) {
    int d = r * 8192 + w * 1024 + lane * 16;
    int lg = d ^ ((lane & 32) ? 32 : 0);   // bit9 of d == lane bit5
    srw[r] = lg >> 7;
    scl[r] = (lg & 127) >> 1;
  }

  f32x4 acc[8][4] = {};

  auto STG = [&](int buf, const __bf16* src, int rows0, int kk0, char* opm,
                 int half) {
#pragma unroll
    for (int r = 0; r < 2; ++r)
      gload16(src + (size_t)(rows0 + half * 128 + srw[r]) * 1024 + kk0 + scl[r],
              opm + buf * 32768 + half * 16384 + r * 8192 + w * 1024);
  };
  auto STGALL = [&](int buf, int kk0) {
    STG(buf, A, m0, kk0, lAm, 0);
    STG(buf, A, m0, kk0, lAm, 1);
    STG(buf, BT, n0, kk0, lBm, 0);
    STG(buf, BT, n0, kk0, lBm, 1);
  };

  STGALL(0, 0);
  asm volatile("s_waitcnt vmcnt(0)" ::: "memory");
  __builtin_amdgcn_s_barrier();

  for (int kt = 0; kt < 16; ++kt) {
    const int c = kt & 1;
    const char* Ah = lAm + c * 32768 + wm * 16384;
    const char* Bh = lBm + c * 32768 + (wn >> 1) * 16384 + bro;
    bf16x8 af[4][2], bfr[2][2];

    // ---- phase 0: read A[0..3], B[0..1]; bulk-stage tile kt+1 ----
#pragma unroll
    for (int i = 0; i < 4; ++i) {
      af[i][0] = *(const bf16x8*)(Ah + i * 2048 + aoff);
      af[i][1] = *(const bf16x8*)(Ah + i * 2048 + 64 + aoff);
    }
#pragma unroll
    for (int j = 0; j < 2; ++j) {
      bfr[j][0] = *(const bf16x8*)(Bh + j * 2048 + aoff);
      bfr[j][1] = *(const bf16x8*)(Bh + j * 2048 + 64 + aoff);
    }
    if (kt + 1 < 16) STGALL(c ^ 1, (kt + 1) * 64);
    __builtin_amdgcn_s_barrier();
    __builtin_amdgcn_s_setprio(1);
#pragma unroll
    for (int i = 0; i < 4; ++i)
#pragma unroll
      for (int j = 0; j < 2; ++j)
#pragma unroll
        for (int kc = 0; kc < 2; ++kc)
          acc[i][j] = mfma16(af[i][kc], bfr[j][kc], acc[i][j]);
    __builtin_amdgcn_s_setprio(0);
    __builtin_amdgcn_s_barrier();

    // ---- phase 1: read B[2..3]; MFMA i0-3 x j2-3 ----
#pragma unroll
    for (int j = 0; j < 2; ++j) {
      bfr[j][0] = *(const bf16x8*)(Bh + (2 + j) * 2048 + aoff);
      bfr[j][1] = *(const bf16x8*)(Bh + (2 + j) * 2048 + 64 + aoff);
    }
    __builtin_amdgcn_s_barrier();
    __builtin_amdgcn_s_setprio(1);
#pragma unroll
    for (int i = 0; i < 4; ++i)
#pragma unroll
      for (int j = 0; j < 2; ++j)
#pragma unroll
        for (int kc = 0; kc < 2; ++kc)
          acc[i][2 + j] = mfma16(af[i][kc], bfr[j][kc], acc[i][2 + j]);
    __builtin_amdgcn_s_setprio(0);
    __builtin_amdgcn_s_barrier();

    // ---- phase 2: read A[4..7]; MFMA i4-7 x j2-3 ----
#pragma unroll
    for (int i = 0; i < 4; ++i) {
      af[i][0] = *(const bf16x8*)(Ah + (4 + i) * 2048 + aoff);
      af[i][1] = *(const bf16x8*)(Ah + (4 + i) * 2048 + 64 + aoff);
    }
    __builtin_amdgcn_s_barrier();
    __builtin_amdgcn_s_setprio(1);
#pragma unroll
    for (int i = 0; i < 4; ++i)
#pragma unroll
      for (int j = 0; j < 2; ++j)
#pragma unroll
        for (int kc = 0; kc < 2; ++kc)
          acc[4 + i][2 + j] = mfma16(af[i][kc], bfr[j][kc], acc[4 + i][2 + j]);
    __builtin_amdgcn_s_setprio(0);
    __builtin_amdgcn_s_barrier();

    // ---- phase 3: read B[0..1]; MFMA i4-7 x j0-1; vmcnt; bar ----
#pragma unroll
    for (int j = 0; j < 2; ++j) {
      bfr[j][0] = *(const bf16x8*)(Bh + j * 2048 + aoff);
      bfr[j][1] = *(const bf16x8*)(Bh + j * 2048 + 64 + aoff);
    }
    __builtin_amdgcn_s_barrier();
    __builtin_amdgcn_s_setprio(1);
#pragma unroll
    for (int i = 0; i < 4; ++i)
#pragma unroll
      for (int j = 0; j < 2; ++j)
#pragma unroll
        for (int kc = 0; kc < 2; ++kc)
          acc[4 + i][j] = mfma16(af[i][kc], bfr[j][kc], acc[4 + i][j]);
    __builtin_amdgcn_s_setprio(0);
    if (kt + 1 < 16) asm volatile("s_waitcnt vmcnt(0)" ::: "memory");
    __builtin_amdgcn_s_barrier();
  }

  // epilogue: scatter to q/k/vT (round-9 proven pattern, 8x4 frags)
#pragma unroll
  for (int j = 0; j < 4; ++j) {
    int n = n0 + wn * 64 + j * 16 + rA;
    float bv = bias[n];
    int sec = n >> 10, nn = n & 1023;
    int h = nn >> 6, d = nn & 63;
#pragma unroll
    for (int i = 0; i < 8; ++i) {
#pragma unroll
      for (int e = 0; e < 4; ++e) {
        int m = m0 + wm * 128 + i * 16 + (lane >> 4) * 4 + e;
        float v = acc[i][j][e] + bv;
        int b = m >> 11, tt = m & 2047;
        if (sec == 0)
          qb[(((size_t)(b * 16 + h)) * 2048 + tt) * 64 + d] = (__bf16)(v * QSCALE);
        else if (sec == 1)
          kb[(((size_t)(b * 16 + h)) * 2048 + tt) * 64 + d] = (__bf16)v;
        else
          vtb[(((size_t)(b * 16 + h)) * 64 + d) * 2048 + tt] = (__bf16)v;
      }
    }
  }
}

// ------- proj GEMM: 64x128 tile (2 blocks/CU for the small shape) -------
__global__ __launch_bounds__(256) void gemm_proj(
    const __bf16* __restrict__ A, const __bf16* __restrict__ BT,
    const float* __restrict__ bias, float* __restrict__ outF,
    int M, int N, int K) {
  __shared__ __align__(16) __bf16 lA[2][64 * 32];
  __shared__ __align__(16) __bf16 lB[2][128 * 32];
  const int t = threadIdx.x;
  const int w = t >> 6, lane = t & 63;
  const int m0 = blockIdx.x * 64, n0 = blockIdx.y * 128;
  const int wr = (w >> 1) * 32, wc = (w & 1) * 64;

  f32x4 acc[2][4] = {};

  const int rA = lane & 15;
  const int kk = (lane >> 4) * 8;

  auto STAGE = [&](int buf, int k0) {
    {
      int row = t >> 2, cc = t & 3;
      gload16(A + (size_t)(m0 + row) * K + k0 + cc * 8,
              &lA[buf][(w * 64) * 8]);
    }
#pragma unroll
    for (int r = 0; r < 2; ++r) {
      int c = r * 256 + t;
      int row = c >> 2, cc = c & 3;
      gload16(BT + (size_t)(n0 + row) * K + k0 + cc * 8,
              &lB[buf][(r * 256 + w * 64) * 8]);
    }
  };

  STAGE(0, 0);
  int cur = 0;
  for (int k0 = 0; k0 < K; k0 += 32, cur ^= 1) {
    __syncthreads();
    if (k0 + 32 < K) STAGE(cur ^ 1, k0 + 32);
    bf16x8 af[2], bfr[4];
#pragma unroll
    for (int i = 0; i < 2; ++i)
      af[i] = *(const bf16x8*)&lA[cur][(wr + i * 16 + rA) * 32 + kk];
#pragma unroll
    for (int j = 0; j < 4; ++j)
      bfr[j] = *(const bf16x8*)&lB[cur][(wc + j * 16 + rA) * 32 + kk];
#pragma unroll
    for (int i = 0; i < 2; ++i)
#pragma unroll
      for (int j = 0; j < 4; ++j)
        acc[i][j] = mfma16(af[i], bfr[j], acc[i][j]);
  }

  const int colb = n0 + wc + rA;
  const int rowb = m0 + wr + (lane >> 4) * 4;
#pragma unroll
  for (int j = 0; j < 4; ++j) {
    int n = colb + j * 16;
    float bv = bias[n];
#pragma unroll
    for (int i = 0; i < 2; ++i) {
#pragma unroll
      for (int e = 0; e < 4; ++e) {
        int m = rowb + i * 16 + e;
        outF[(size_t)m * N + n] = acc[i][j][e] + bv;
      }
    }
  }
}

// ------- flash attention: 32x32 MFMA, in-register P, key-split waves ---------
__global__ __launch_bounds__(256) void attn_k(
    const __bf16* __restrict__ q, const __bf16* __restrict__ k,
    const __bf16* __restrict__ vt, const float* __restrict__ tbl,
    __bf16* __restrict__ y) {
  // carve: lK[2] @0 (2x8KB) | lV[2] @16K (2x8KB) | lb[2] @32K (2x192 f32)
  __shared__ __align__(16) char smem[2 * 8192 + 2 * 8192 + 2 * 768];
  float* lbuf = (float*)(smem + 32768);

  const int t = threadIdx.x, w = t >> 6, lane = t & 63;
  const int bh = blockIdx.x, b = bh >> 4, h = bh & 15;
  const int qt64 = 31 - blockIdx.y;               // longest blocks first
  const int qs = w >> 1, ks = w & 1;
  const int ncol = lane & 31, hi = lane >> 5;
  const int swl = ncol & 7;                       // row&7 for all frag rows

  const __bf16* qp = q + (size_t)bh * 2048 * 64;
  const __bf16* kp = k + (size_t)bh * 2048 * 64;
  const __bf16* vp = vt + (size_t)bh * 64 * 2048;
  const float* tb = tbl + h * 2048;
  const float bconst = tb[2047] - FIXMAX;  // bucket-31 bias, fixed shift folded

  // Q B-frags: lane holds Q[qt64*64 + qs*32 + ncol][dc*16 + hi*8 + j]
  bf16x8 qf[4];
  {
    const __bf16* qr = qp + (size_t)(qt64 * 64 + qs * 32 + ncol) * 64 + hi * 8;
#pragma unroll
    for (int dc = 0; dc < 4; ++dc) qf[dc] = *(const bf16x8*)(qr + dc * 16);
  }

  f32x16 O0 = {}, O1 = {};
  float lsum = 0.f;
  const int ibase = 95 + 32 * (qs - ks) - 4 * hi + ncol;  // lb index base

  auto STAGE = [&](int buf, int jt) {
#pragma unroll
    for (int r = 0; r < 2; ++r) {
      int c = r * 256 + t;
      int row = c >> 3, cc = c & 7;
      int sc = cc ^ (row & 7);        // pre-swizzled source chunk
      gload16(kp + (size_t)(jt * 64 + row) * 64 + sc * 8,
              smem + buf * 8192 + (r * 256 + w * 64) * 16);
      gload16(vp + (size_t)row * 2048 + jt * 64 + sc * 8,
              smem + 16384 + buf * 8192 + (r * 256 + w * 64) * 16);
    }
    int dtj = qt64 - jt;
    if (dtj < 3 && t < 192) {         // bias window only near the diagonal
      int rb = dtj * 64 - 95 + t;
      lbuf[buf * 192 + t] = tb[rb < 0 ? 0 : rb] - FIXMAX;
    }
  };

  STAGE(0, 0);
  int cur = 0;
  for (int jt = 0; jt <= qt64; ++jt, cur ^= 1) {
    const int dt = qt64 - jt;
    const int rel = 2 * dt + qs - ks;
    __syncthreads();                        // buf[cur] ready (vmcnt drained)
    if (jt < qt64) STAGE(cur ^ 1, jt + 1);  // prefetch flies under compute
    if (rel < 0) continue;                  // wave-uniform: block fully masked

    const char* Kc = smem + cur * 8192;
    const char* Vc = smem + 16384 + cur * 8192;
    const float* lbc = lbuf + cur * 192;

    // C-init = bias - FIXMAX (and -1e30 on masked diagonal elements)
    f32x16 s;
    if (rel >= 5) {
#pragma unroll
      for (int r = 0; r < 16; ++r) s[r] = bconst;
    } else {
#pragma unroll
      for (int r = 0; r < 16; ++r) {
        int cr8 = (r & 3) + 8 * (r >> 2);       // crow without hi term
        float v = lbc[ibase - cr8];
        if (rel == 0 && ncol < cr8 + 4 * hi) v = -1e30f;
        s[r] = v;
      }
    }
    // S^T += K Q^T : A-frag K[key=ks*32+ncol][dc*16 + hi*8..], B-frag Q
    const char* Kb = Kc + (ks * 32 + ncol) * 128;
#pragma unroll
    for (int dc = 0; dc < 4; ++dc) {
      bf16x8 kf = *(const bf16x8*)(Kb + (((dc * 2 + hi) ^ swl) << 4));
      s = mfma32(kf, qf[dc], s);
    }
    // P = exp2(S); pack to PV A-frags in-register (no LDS bounce)
    float p[16];
#pragma unroll
    for (int r = 0; r < 16; ++r) {
      p[r] = exp2a(s[r]);
      lsum += p[r];
    }
#pragma unroll
    for (int s16 = 0; s16 < 2; ++s16) {
      unsigned we0 = cvtpk(p[8 * s16 + 0], p[8 * s16 + 1]);
      unsigned we1 = cvtpk(p[8 * s16 + 2], p[8 * s16 + 3]);
      unsigned wo0 = cvtpk(p[8 * s16 + 4], p[8 * s16 + 5]);
      unsigned wo1 = cvtpk(p[8 * s16 + 6], p[8 * s16 + 7]);
      u32x2 r0 = __builtin_amdgcn_permlane32_swap(we0, wo0, false, false);
      u32x2 r1 = __builtin_amdgcn_permlane32_swap(we1, wo1, false, false);
      u32x4 aw = {r0[0], r1[0], r0[1], r1[1]};
      bf16x8 af = __builtin_bit_cast(bf16x8, aw);
      // O += P V : B-frag V[key=(ks*2+s16)*16 + hi*8..][db*32+ncol]
#pragma unroll
      for (int db = 0; db < 2; ++db) {
        const char* Vb = Vc + (db * 32 + ncol) * 128;
        bf16x8 vf = *(const bf16x8*)(Vb +
            ((((ks * 2 + s16) * 2 + hi) ^ swl) << 4));
        if (db == 0) O0 = mfma32(af, vf, O0);
        else         O1 = mfma32(af, vf, O1);
      }
    }
  }

  // combine key-split partials: ks=1 waves export O/lsum via LDS, ks=0 add
  lsum += __shfl_xor(lsum, 32);
  __syncthreads();                    // all K/V reads done; smem reusable
  float* ls = (float*)(smem + 32768); // 512B lsum scratch (lb dead now)
  if (ks) {
    char* dst = smem + qs * 8192 + lane * 128;
#pragma unroll
    for (int c = 0; c < 4; ++c) {
      f32x4 v0 = {O0[4 * c], O0[4 * c + 1], O0[4 * c + 2], O0[4 * c + 3]};
      *(f32x4*)(dst + ((c ^ swl) << 4)) = v0;
      f32x4 v1 = {O1[4 * c], O1[4 * c + 1], O1[4 * c + 2], O1[4 * c + 3]};
      *(f32x4*)(dst + (((c + 4) ^ swl) << 4)) = v1;
    }
    ls[qs * 64 + lane] = lsum;
  }
  __syncthreads();
  if (!ks) {
    lsum += ls[qs * 64 + lane];
    const char* src = smem + qs * 8192 + lane * 128;
#pragma unroll
    for (int c = 0; c < 4; ++c) {
      f32x4 v0 = *(const f32x4*)(src + ((c ^ swl) << 4));
      f32x4 v1 = *(const f32x4*)(src + (((c + 4) ^ swl) << 4));
#pragma unroll
      for (int e = 0; e < 4; ++e) {
        O0[4 * c + e] += v0[e];
        O1[4 * c + e] += v1[e];
      }
    }
    // epilogue: lanes l and l^32 held complementary key-halves (combined)
    float rinv = 1.0f / lsum;         // for own qrow = ncol
#pragma unroll
    for (int r = 0; r < 16; ++r) {
      int cr = (r & 3) + 8 * (r >> 2) + 4 * hi;   // output qrow (C/D layout)
      float ri = __shfl(rinv, cr);                // lane cr owns qrow cr
      int row = qt64 * 64 + qs * 32 + cr;
      size_t base = ((size_t)(b * 2048 + row)) * 1024 + h * 64 + ncol;
      y[base]      = (__bf16)(O0[r] * ri);
      y[base + 32] = (__bf16)(O1[r] * ri);
    }
  }
}

// ---------------- launch ----------------

extern "C" void kernel_launch(void* const* d_in, const int* in_sizes, int n_in,
                              void* d_out, int out_size, void* d_ws, size_t ws_size,
                              hipStream_t stream) {
  const float* x = (const float*)d_in[0];
  const float* W_attn = (const float*)d_in[1];
  const float* b_attn = (const float*)d_in[2];
  const float* W_proj = (const float*)d_in[3];
  const float* b_proj = (const float*)d_in[4];
  const float* bias_table = (const float*)d_in[5];
  float* out = (float*)d_out;

  char* ws = (char*)d_ws;
  __bf16* xb   = (__bf16*)(ws + 0);          // 4096x1024           8 MB
  __bf16* WaT  = (__bf16*)(ws + 8388608);    // 3072x1024           6 MB
  __bf16* WpT  = (__bf16*)(ws + 14680064);   // 1024x1024           2 MB
  __bf16* qb   = (__bf16*)(ws + 16777216);   // [B,H,T,D]           8 MB
  __bf16* kb   = (__bf16*)(ws + 25165824);   // [B,H,T,D]           8 MB
  __bf16* vtb  = (__bf16*)(ws + 33554432);   // [B,H,D,T]           8 MB
  __bf16* yb   = (__bf16*)(ws + 41943040);   // [B,T,C]             8 MB
  float*  tbl  = (float*)(ws + 50331648);    // [H,T] bias*log2e  128 KB

  prep_k<<<8320, 256, 0, stream>>>(x, W_attn, W_proj, bias_table,
                                   xb, WaT, WpT, tbl);
  gemm_qkv<<<dim3(16, 12), 512, 0, stream>>>(xb, WaT, b_attn, qb, kb, vtb);
  attn_k<<<dim3(32, 32), 256, 0, stream>>>(qb, kb, vtb, tbl, yb);
  gemm_proj<<<dim3(64, 8), 256, 0, stream>>>(yb, WpT, b_proj, out,
                                             4096, 1024, 1024);
}

// Round 13
// 130.951 us; speedup vs baseline: 1.0180x; 1.0180x over previous
//
#include <hip/hip_runtime.h>
#include <hip/hip_bf16.h>
#include <math.h>

typedef __attribute__((ext_vector_type(4))) float f32x4;
typedef __attribute__((ext_vector_type(16))) float f32x16;
typedef __attribute__((ext_vector_type(8))) __bf16 bf16x8;
typedef __attribute__((ext_vector_type(4))) __bf16 bf16x4;
typedef __attribute__((ext_vector_type(4))) unsigned int u32x4;
typedef __attribute__((ext_vector_type(2))) unsigned int u32x2;

#define DEVI __device__ __forceinline__

DEVI f32x4 mfma16(bf16x8 a, bf16x8 b, f32x4 c) {
  return __builtin_amdgcn_mfma_f32_16x16x32_bf16(a, b, c, 0, 0, 0);
}
DEVI f32x16 mfma32(bf16x8 a, bf16x8 b, f32x16 c) {
  return __builtin_amdgcn_mfma_f32_32x32x16_bf16(a, b, c, 0, 0, 0);
}

// async global->LDS, 16B per lane; LDS dest = wave-uniform base + lane*16
DEVI void gload16(const void* g, void* l) {
  __builtin_amdgcn_global_load_lds(
      (const __attribute__((address_space(1))) void*)g,
      (__attribute__((address_space(3))) void*)l, 16, 0, 0);
}

DEVI float exp2a(float x) {  // single v_exp_f32 (exp2); inputs are log2-domain
  float r;
  asm("v_exp_f32 %0, %1" : "=v"(r) : "v"(x));
  return r;
}
DEVI unsigned cvtpk(float lo, float hi) {  // u32 = {bf16(lo), bf16(hi)}
  unsigned r;
  asm("v_cvt_pk_bf16_f32 %0, %1, %2" : "=v"(r) : "v"(lo), "v"(hi));
  return r;
}

#define LOG2E 1.4426950408889634f
#define QSCALE 0.18033688011110793f  /* 0.125 * log2(e) */
#define FIXMAX 8.0f  /* fixed softmax shift: S<<8 always; ratio O/lsum exact */

// ---------------- fused prep: x->bf16, W transposes, bias table ----------------
__global__ __launch_bounds__(256) void prep_k(
    const float* __restrict__ x, const float* __restrict__ W_attn,
    const float* __restrict__ W_proj, const float* __restrict__ bt,
    __bf16* __restrict__ xb, __bf16* __restrict__ WaT,
    __bf16* __restrict__ WpT, float* __restrict__ tbl) {
  __shared__ float tile[32][33];
  int bid = blockIdx.x;
  const int t = threadIdx.x;
  if (bid < 4096) {
    int i = (bid * 256 + t) * 4;
    float4 v = *(const float4*)&x[i];
    bf16x4 o = {(__bf16)v.x, (__bf16)v.y, (__bf16)v.z, (__bf16)v.w};
    *(bf16x4*)&xb[i] = o;
    return;
  }
  bid -= 4096;
  if (bid < 4096) {
    const float* in;
    __bf16* out;
    int Cc, bx, by;
    if (bid < 3072) {
      in = W_attn; out = WaT; Cc = 3072; bx = bid % 96; by = bid / 96;
    } else {
      int b2 = bid - 3072;
      in = W_proj; out = WpT; Cc = 1024; bx = b2 % 32; by = b2 / 32;
    }
    const int R = 1024;
    int tx = t & 31, ty = t >> 5;
    int xcol = bx * 32 + tx;
    for (int r = ty; r < 32; r += 8)
      tile[r][tx] = in[(size_t)(by * 32 + r) * Cc + xcol];
    __syncthreads();
    int xo = by * 32 + tx;
    for (int r = ty; r < 32; r += 8)
      out[(size_t)(bx * 32 + r) * R + xo] = (__bf16)tile[tx][r];
    return;
  }
  bid -= 4096;
  int idx = bid * 256 + t;  // h*2048 + rp
  int h = idx >> 11, rp = idx & 2047;
  int bucket;
  if (rp < 16) {
    bucket = rp;
  } else {
    float v = (logf((float)rp * 0.0625f) / 2.0794415416798357f) * 16.0f;
    bucket = 16 + (int)v;
    if (bucket > 31) bucket = 31;
  }
  tbl[idx] = bt[bucket * 16 + h] * LOG2E;
}

// ------- QKV GEMM: 256x256 8-phase, BK=64, conflict-free chunk swizzle -------
// 512 thr = 8 waves (2M x 4N), per-wave C = 128x64 (acc[8][4]).
// LDS 128KB: {A,B} x 2dbuf x 2half x [128 rows][64 k] bf16 (128B rows).
// Swizzle: 16B chunk index ^= (row&7)  [attn-proven; rows 0-7 hit all 32
// banks, rows 8-15 repeat = 2-way = free]. Stage side writes linear dest,
// source chunk = lin_chunk ^ (row&7). Verified: elem(row5,k19) stage byte
// 758 == read byte 758 (incl. B sub-panel +8192 case; 64 ≡ 0 mod 8).
// Staging: 8 gload16 of tile kt+1 at phase 0; vmcnt(0) at end of phase 3.
// B[0..1] frags held in regs across phases (no phase-3 re-read).
__global__ __launch_bounds__(512) void gemm_qkv(
    const __bf16* __restrict__ A, const __bf16* __restrict__ BT,
    const float* __restrict__ bias,
    __bf16* __restrict__ qb, __bf16* __restrict__ kb, __bf16* __restrict__ vtb) {
  __shared__ __align__(16) char lAm[65536];
  __shared__ __align__(16) char lBm[65536];
  const int t = threadIdx.x, w = t >> 6, lane = t & 63;
  const int wm = w >> 2, wn = w & 3;
  const int m0 = blockIdx.x * 256, n0 = blockIdx.y * 256;
  const int rA = lane & 15;
  const int sw7 = rA & 7;                    // row&7 for all frag rows
  const int ckbase = lane >> 4;              // chunk = ckbase + kc*4
  const int bro = (wn & 1) * 8192;           // B row-base within half (bytes)

  // staging decode: thread's linear 16B dest -> (row, source chunk)
  int srw[2], scl[2];
#pragma unroll
  for (int r = 0; r < 2; ++r) {
    int d = r * 8192 + w * 1024 + lane * 16;
    srw[r] = d >> 7;                          // row 0..127
    scl[r] = (((d >> 4) & 7) ^ (srw[r] & 7)) * 8;  // source k-offset (elems)
  }

  f32x4 acc[8][4] = {};

  auto STG = [&](int buf, const __bf16* src, int rows0, int kk0, char* opm,
                 int half) {
#pragma unroll
    for (int r = 0; r < 2; ++r)
      gload16(src + (size_t)(rows0 + half * 128 + srw[r]) * 1024 + kk0 + scl[r],
              opm + buf * 32768 + half * 16384 + r * 8192 + w * 1024);
  };
  auto STGALL = [&](int buf, int kk0) {
    STG(buf, A, m0, kk0, lAm, 0);
    STG(buf, A, m0, kk0, lAm, 1);
    STG(buf, BT, n0, kk0, lBm, 0);
    STG(buf, BT, n0, kk0, lBm, 1);
  };
  // frag byte offset within half-tile: row rl, chunk = ckbase + kc*4
  auto FOFF = [&](int rl, int kc) {
    return rl * 128 + (((ckbase + kc * 4) ^ sw7) << 4);
  };

  STGALL(0, 0);
  asm volatile("s_waitcnt vmcnt(0)" ::: "memory");
  __builtin_amdgcn_s_barrier();

  for (int kt = 0; kt < 16; ++kt) {
    const int c = kt & 1;
    const char* Ah = lAm + c * 32768 + wm * 16384;
    const char* Bh = lBm + c * 32768 + (wn >> 1) * 16384 + bro;
    bf16x8 af[4][2], b01[2][2], b23[2][2];

    // ---- phase 0: read A[0..3], B[0..1]; bulk-stage tile kt+1 ----
#pragma unroll
    for (int i = 0; i < 4; ++i)
#pragma unroll
      for (int kc = 0; kc < 2; ++kc)
        af[i][kc] = *(const bf16x8*)(Ah + FOFF(i * 16 + rA, kc));
#pragma unroll
    for (int j = 0; j < 2; ++j)
#pragma unroll
      for (int kc = 0; kc < 2; ++kc)
        b01[j][kc] = *(const bf16x8*)(Bh + FOFF(j * 16 + rA, kc));
    if (kt + 1 < 16) STGALL(c ^ 1, (kt + 1) * 64);
    __builtin_amdgcn_s_barrier();
    __builtin_amdgcn_s_setprio(1);
#pragma unroll
    for (int i = 0; i < 4; ++i)
#pragma unroll
      for (int j = 0; j < 2; ++j)
#pragma unroll
        for (int kc = 0; kc < 2; ++kc)
          acc[i][j] = mfma16(af[i][kc], b01[j][kc], acc[i][j]);
    __builtin_amdgcn_s_setprio(0);
    __builtin_amdgcn_s_barrier();

    // ---- phase 1: read B[2..3]; MFMA i0-3 x j2-3 ----
#pragma unroll
    for (int j = 0; j < 2; ++j)
#pragma unroll
      for (int kc = 0; kc < 2; ++kc)
        b23[j][kc] = *(const bf16x8*)(Bh + FOFF((2 + j) * 16 + rA, kc));
    __builtin_amdgcn_s_barrier();
    __builtin_amdgcn_s_setprio(1);
#pragma unroll
    for (int i = 0; i < 4; ++i)
#pragma unroll
      for (int j = 0; j < 2; ++j)
#pragma unroll
        for (int kc = 0; kc < 2; ++kc)
          acc[i][2 + j] = mfma16(af[i][kc], b23[j][kc], acc[i][2 + j]);
    __builtin_amdgcn_s_setprio(0);
    __builtin_amdgcn_s_barrier();

    // ---- phase 2: read A[4..7]; MFMA i4-7 x j2-3 ----
#pragma unroll
    for (int i = 0; i < 4; ++i)
#pragma unroll
      for (int kc = 0; kc < 2; ++kc)
        af[i][kc] = *(const bf16x8*)(Ah + FOFF((4 + i) * 16 + rA, kc));
    __builtin_amdgcn_s_barrier();
    __builtin_amdgcn_s_setprio(1);
#pragma unroll
    for (int i = 0; i < 4; ++i)
#pragma unroll
      for (int j = 0; j < 2; ++j)
#pragma unroll
        for (int kc = 0; kc < 2; ++kc)
          acc[4 + i][2 + j] = mfma16(af[i][kc], b23[j][kc], acc[4 + i][2 + j]);
    __builtin_amdgcn_s_setprio(0);
    __builtin_amdgcn_s_barrier();

    // ---- phase 3: MFMA i4-7 x j0-1 (held b01); vmcnt; bar ----
    __builtin_amdgcn_s_setprio(1);
#pragma unroll
    for (int i = 0; i < 4; ++i)
#pragma unroll
      for (int j = 0; j < 2; ++j)
#pragma unroll
        for (int kc = 0; kc < 2; ++kc)
          acc[4 + i][j] = mfma16(af[i][kc], b01[j][kc], acc[4 + i][j]);
    __builtin_amdgcn_s_setprio(0);
    if (kt + 1 < 16) asm volatile("s_waitcnt vmcnt(0)" ::: "memory");
    __builtin_amdgcn_s_barrier();
  }

  // epilogue: scatter to q/k/vT (round-9 proven pattern, 8x4 frags)
#pragma unroll
  for (int j = 0; j < 4; ++j) {
    int n = n0 + wn * 64 + j * 16 + rA;
    float bv = bias[n];
    int sec = n >> 10, nn = n & 1023;
    int h = nn >> 6, d = nn & 63;
#pragma unroll
    for (int i = 0; i < 8; ++i) {
#pragma unroll
      for (int e = 0; e < 4; ++e) {
        int m = m0 + wm * 128 + i * 16 + (lane >> 4) * 4 + e;
        float v = acc[i][j][e] + bv;
        int b = m >> 11, tt = m & 2047;
        if (sec == 0)
          qb[(((size_t)(b * 16 + h)) * 2048 + tt) * 64 + d] = (__bf16)(v * QSCALE);
        else if (sec == 1)
          kb[(((size_t)(b * 16 + h)) * 2048 + tt) * 64 + d] = (__bf16)v;
        else
          vtb[(((size_t)(b * 16 + h)) * 64 + d) * 2048 + tt] = (__bf16)v;
      }
    }
  }
}

// ------- proj GEMM: 64x128 tile (2 blocks/CU for the small shape) -------
__global__ __launch_bounds__(256) void gemm_proj(
    const __bf16* __restrict__ A, const __bf16* __restrict__ BT,
    const float* __restrict__ bias, float* __restrict__ outF,
    int M, int N, int K) {
  __shared__ __align__(16) __bf16 lA[2][64 * 32];
  __shared__ __align__(16) __bf16 lB[2][128 * 32];
  const int t = threadIdx.x;
  const int w = t >> 6, lane = t & 63;
  const int m0 = blockIdx.x * 64, n0 = blockIdx.y * 128;
  const int wr = (w >> 1) * 32, wc = (w & 1) * 64;

  f32x4 acc[2][4] = {};

  const int rA = lane & 15;
  const int kk = (lane >> 4) * 8;

  auto STAGE = [&](int buf, int k0) {
    {
      int row = t >> 2, cc = t & 3;
      gload16(A + (size_t)(m0 + row) * K + k0 + cc * 8,
              &lA[buf][(w * 64) * 8]);
    }
#pragma unroll
    for (int r = 0; r < 2; ++r) {
      int c = r * 256 + t;
      int row = c >> 2, cc = c & 3;
      gload16(BT + (size_t)(n0 + row) * K + k0 + cc * 8,
              &lB[buf][(r * 256 + w * 64) * 8]);
    }
  };

  STAGE(0, 0);
  int cur = 0;
  for (int k0 = 0; k0 < K; k0 += 32, cur ^= 1) {
    __syncthreads();
    if (k0 + 32 < K) STAGE(cur ^ 1, k0 + 32);
    bf16x8 af[2], bfr[4];
#pragma unroll
    for (int i = 0; i < 2; ++i)
      af[i] = *(const bf16x8*)&lA[cur][(wr + i * 16 + rA) * 32 + kk];
#pragma unroll
    for (int j = 0; j < 4; ++j)
      bfr[j] = *(const bf16x8*)&lB[cur][(wc + j * 16 + rA) * 32 + kk];
#pragma unroll
    for (int i = 0; i < 2; ++i)
#pragma unroll
      for (int j = 0; j < 4; ++j)
        acc[i][j] = mfma16(af[i], bfr[j], acc[i][j]);
  }

  const int colb = n0 + wc + rA;
  const int rowb = m0 + wr + (lane >> 4) * 4;
#pragma unroll
  for (int j = 0; j < 4; ++j) {
    int n = colb + j * 16;
    float bv = bias[n];
#pragma unroll
    for (int i = 0; i < 2; ++i) {
#pragma unroll
      for (int e = 0; e < 4; ++e) {
        int m = rowb + i * 16 + e;
        outF[(size_t)m * N + n] = acc[i][j][e] + bv;
      }
    }
  }
}

// ------- flash attention: 32x32 MFMA, in-register P, key-split waves ---------
__global__ __launch_bounds__(256) void attn_k(
    const __bf16* __restrict__ q, const __bf16* __restrict__ k,
    const __bf16* __restrict__ vt, const float* __restrict__ tbl,
    __bf16* __restrict__ y) {
  // carve: lK[2] @0 (2x8KB) | lV[2] @16K (2x8KB) | lb[2] @32K (2x192 f32)
  __shared__ __align__(16) char smem[2 * 8192 + 2 * 8192 + 2 * 768];
  float* lbuf = (float*)(smem + 32768);

  const int t = threadIdx.x, w = t >> 6, lane = t & 63;
  const int bh = blockIdx.x, b = bh >> 4, h = bh & 15;
  const int qt64 = 31 - blockIdx.y;               // longest blocks first
  const int qs = w >> 1, ks = w & 1;
  const int ncol = lane & 31, hi = lane >> 5;
  const int swl = ncol & 7;                       // row&7 for all frag rows

  const __bf16* qp = q + (size_t)bh * 2048 * 64;
  const __bf16* kp = k + (size_t)bh * 2048 * 64;
  const __bf16* vp = vt + (size_t)bh * 64 * 2048;
  const float* tb = tbl + h * 2048;
  const float bconst = tb[2047] - FIXMAX;  // bucket-31 bias, fixed shift folded

  // Q B-frags: lane holds Q[qt64*64 + qs*32 + ncol][dc*16 + hi*8 + j]
  bf16x8 qf[4];
  {
    const __bf16* qr = qp + (size_t)(qt64 * 64 + qs * 32 + ncol) * 64 + hi * 8;
#pragma unroll
    for (int dc = 0; dc < 4; ++dc) qf[dc] = *(const bf16x8*)(qr + dc * 16);
  }

  f32x16 O0 = {}, O1 = {};
  float lsum = 0.f;
  const int ibase = 95 + 32 * (qs - ks) - 4 * hi + ncol;  // lb index base

  auto STAGE = [&](int buf, int jt) {
#pragma unroll
    for (int r = 0; r < 2; ++r) {
      int c = r * 256 + t;
      int row = c >> 3, cc = c & 7;
      int sc = cc ^ (row & 7);        // pre-swizzled source chunk
      gload16(kp + (size_t)(jt * 64 + row) * 64 + sc * 8,
              smem + buf * 8192 + (r * 256 + w * 64) * 16);
      gload16(vp + (size_t)row * 2048 + jt * 64 + sc * 8,
              smem + 16384 + buf * 8192 + (r * 256 + w * 64) * 16);
    }
    int dtj = qt64 - jt;
    if (dtj < 3 && t < 192) {         // bias window only near the diagonal
      int rb = dtj * 64 - 95 + t;
      lbuf[buf * 192 + t] = tb[rb < 0 ? 0 : rb] - FIXMAX;
    }
  };

  STAGE(0, 0);
  int cur = 0;
  for (int jt = 0; jt <= qt64; ++jt, cur ^= 1) {
    const int dt = qt64 - jt;
    const int rel = 2 * dt + qs - ks;
    __syncthreads();                        // buf[cur] ready (vmcnt drained)
    if (jt < qt64) STAGE(cur ^ 1, jt + 1);  // prefetch flies under compute
    if (rel < 0) continue;                  // wave-uniform: block fully masked

    const char* Kc = smem + cur * 8192;
    const char* Vc = smem + 16384 + cur * 8192;
    const float* lbc = lbuf + cur * 192;

    // C-init = bias - FIXMAX (and -1e30 on masked diagonal elements)
    f32x16 s;
    if (rel >= 5) {
#pragma unroll
      for (int r = 0; r < 16; ++r) s[r] = bconst;
    } else {
#pragma unroll
      for (int r = 0; r < 16; ++r) {
        int cr8 = (r & 3) + 8 * (r >> 2);       // crow without hi term
        float v = lbc[ibase - cr8];
        if (rel == 0 && ncol < cr8 + 4 * hi) v = -1e30f;
        s[r] = v;
      }
    }
    // S^T += K Q^T : A-frag K[key=ks*32+ncol][dc*16 + hi*8..], B-frag Q
    const char* Kb = Kc + (ks * 32 + ncol) * 128;
#pragma unroll
    for (int dc = 0; dc < 4; ++dc) {
      bf16x8 kf = *(const bf16x8*)(Kb + (((dc * 2 + hi) ^ swl) << 4));
      s = mfma32(kf, qf[dc], s);
    }
    // P = exp2(S); pack to PV A-frags in-register (no LDS bounce)
    float p[16];
#pragma unroll
    for (int r = 0; r < 16; ++r) {
      p[r] = exp2a(s[r]);
      lsum += p[r];
    }
#pragma unroll
    for (int s16 = 0; s16 < 2; ++s16) {
      unsigned we0 = cvtpk(p[8 * s16 + 0], p[8 * s16 + 1]);
      unsigned we1 = cvtpk(p[8 * s16 + 2], p[8 * s16 + 3]);
      unsigned wo0 = cvtpk(p[8 * s16 + 4], p[8 * s16 + 5]);
      unsigned wo1 = cvtpk(p[8 * s16 + 6], p[8 * s16 + 7]);
      u32x2 r0 = __builtin_amdgcn_permlane32_swap(we0, wo0, false, false);
      u32x2 r1 = __builtin_amdgcn_permlane32_swap(we1, wo1, false, false);
      u32x4 aw = {r0[0], r1[0], r0[1], r1[1]};
      bf16x8 af = __builtin_bit_cast(bf16x8, aw);
      // O += P V : B-frag V[key=(ks*2+s16)*16 + hi*8..][db*32+ncol]
#pragma unroll
      for (int db = 0; db < 2; ++db) {
        const char* Vb = Vc + (db * 32 + ncol) * 128;
        bf16x8 vf = *(const bf16x8*)(Vb +
            ((((ks * 2 + s16) * 2 + hi) ^ swl) << 4));
        if (db == 0) O0 = mfma32(af, vf, O0);
        else         O1 = mfma32(af, vf, O1);
      }
    }
  }

  // combine key-split partials: ks=1 waves export O/lsum via LDS, ks=0 add
  lsum += __shfl_xor(lsum, 32);
  __syncthreads();                    // all K/V reads done; smem reusable
  float* ls = (float*)(smem + 32768); // 512B lsum scratch (lb dead now)
  if (ks) {
    char* dst = smem + qs * 8192 + lane * 128;
#pragma unroll
    for (int c = 0; c < 4; ++c) {
      f32x4 v0 = {O0[4 * c], O0[4 * c + 1], O0[4 * c + 2], O0[4 * c + 3]};
      *(f32x4*)(dst + ((c ^ swl) << 4)) = v0;
      f32x4 v1 = {O1[4 * c], O1[4 * c + 1], O1[4 * c + 2], O1[4 * c + 3]};
      *(f32x4*)(dst + (((c + 4) ^ swl) << 4)) = v1;
    }
    ls[qs * 64 + lane] = lsum;
  }
  __syncthreads();
  if (!ks) {
    lsum += ls[qs * 64 + lane];
    const char* src = smem + qs * 8192 + lane * 128;
#pragma unroll
    for (int c = 0; c < 4; ++c) {
      f32x4 v0 = *(const f32x4*)(src + ((c ^ swl) << 4));
      f32x4 v1 = *(const f32x4*)(src + (((c + 4) ^ swl) << 4));
#pragma unroll
      for (int e = 0; e < 4; ++e) {
        O0[4 * c + e] += v0[e];
        O1[4 * c + e] += v1[e];
      }
    }
    // epilogue: lanes l and l^32 held complementary key-halves (combined)
    float rinv = 1.0f / lsum;         // for own qrow = ncol
#pragma unroll
    for (int r = 0; r < 16; ++r) {
      int cr = (r & 3) + 8 * (r >> 2) + 4 * hi;   // output qrow (C/D layout)
      float ri = __shfl(rinv, cr);                // lane cr owns qrow cr
      int row = qt64 * 64 + qs * 32 + cr;
      size_t base = ((size_t)(b * 2048 + row)) * 1024 + h * 64 + ncol;
      y[base]      = (__bf16)(O0[r] * ri);
      y[base + 32] = (__bf16)(O1[r] * ri);
    }
  }
}

// ---------------- launch ----------------

extern "C" void kernel_launch(void* const* d_in, const int* in_sizes, int n_in,
                              void* d_out, int out_size, void* d_ws, size_t ws_size,
                              hipStream_t stream) {
  const float* x = (const float*)d_in[0];
  const float* W_attn = (const float*)d_in[1];
  const float* b_attn = (const float*)d_in[2];
  const float* W_proj = (const float*)d_in[3];
  const float* b_proj = (const float*)d_in[4];
  const float* bias_table = (const float*)d_in[5];
  float* out = (float*)d_out;

  char* ws = (char*)d_ws;
  __bf16* xb   = (__bf16*)(ws + 0);          // 4096x1024           8 MB
  __bf16* WaT  = (__bf16*)(ws + 8388608);    // 3072x1024           6 MB
  __bf16* WpT  = (__bf16*)(ws + 14680064);   // 1024x1024           2 MB
  __bf16* qb   = (__bf16*)(ws + 16777216);   // [B,H,T,D]           8 MB
  __bf16* kb   = (__bf16*)(ws + 25165824);   // [B,H,T,D]           8 MB
  __bf16* vtb  = (__bf16*)(ws + 33554432);   // [B,H,D,T]           8 MB
  __bf16* yb   = (__bf16*)(ws + 41943040);   // [B,T,C]             8 MB
  float*  tbl  = (float*)(ws + 50331648);    // [H,T] bias*log2e  128 KB

  prep_k<<<8320, 256, 0, stream>>>(x, W_attn, W_proj, bias_table,
                                   xb, WaT, WpT, tbl);
  gemm_qkv<<<dim3(16, 12), 512, 0, stream>>>(xb, WaT, b_attn, qb, kb, vtb);
  attn_k<<<dim3(32, 32), 256, 0, stream>>>(qb, kb, vtb, tbl, yb);
  gemm_proj<<<dim3(64, 8), 256, 0, stream>>>(yb, WpT, b_proj, out,
                                             4096, 1024, 1024);
}

// Round 14
// 109.741 us; speedup vs baseline: 1.2148x; 1.1933x over previous
//
#include <hip/hip_runtime.h>
#include <hip/hip_bf16.h>
#include <math.h>

typedef __attribute__((ext_vector_type(4))) float f32x4;
typedef __attribute__((ext_vector_type(16))) float f32x16;
typedef __attribute__((ext_vector_type(8))) __bf16 bf16x8;
typedef __attribute__((ext_vector_type(4))) __bf16 bf16x4;
typedef __attribute__((ext_vector_type(4))) unsigned int u32x4;
typedef __attribute__((ext_vector_type(2))) unsigned int u32x2;

#define DEVI __device__ __forceinline__

DEVI f32x4 mfma16(bf16x8 a, bf16x8 b, f32x4 c) {
  return __builtin_amdgcn_mfma_f32_16x16x32_bf16(a, b, c, 0, 0, 0);
}
DEVI f32x16 mfma32(bf16x8 a, bf16x8 b, f32x16 c) {
  return __builtin_amdgcn_mfma_f32_32x32x16_bf16(a, b, c, 0, 0, 0);
}

// async global->LDS, 16B per lane; LDS dest = wave-uniform base + lane*16
DEVI void gload16(const void* g, void* l) {
  __builtin_amdgcn_global_load_lds(
      (const __attribute__((address_space(1))) void*)g,
      (__attribute__((address_space(3))) void*)l, 16, 0, 0);
}

DEVI float exp2a(float x) {  // single v_exp_f32 (exp2); inputs are log2-domain
  float r;
  asm("v_exp_f32 %0, %1" : "=v"(r) : "v"(x));
  return r;
}
DEVI unsigned cvtpk(float lo, float hi) {  // u32 = {bf16(lo), bf16(hi)}
  unsigned r;
  asm("v_cvt_pk_bf16_f32 %0, %1, %2" : "=v"(r) : "v"(lo), "v"(hi));
  return r;
}

#define LOG2E 1.4426950408889634f
#define QSCALE 0.18033688011110793f  /* 0.125 * log2(e) */
#define FIXMAX 8.0f  /* fixed softmax shift: S<<8 always; ratio O/lsum exact */

// ---------------- fused prep: x->bf16, W transposes, bias table ----------------
__global__ __launch_bounds__(256) void prep_k(
    const float* __restrict__ x, const float* __restrict__ W_attn,
    const float* __restrict__ W_proj, const float* __restrict__ bt,
    __bf16* __restrict__ xb, __bf16* __restrict__ WaT,
    __bf16* __restrict__ WpT, float* __restrict__ tbl) {
  __shared__ float tile[32][33];
  int bid = blockIdx.x;
  const int t = threadIdx.x;
  if (bid < 4096) {
    int i = (bid * 256 + t) * 4;
    float4 v = *(const float4*)&x[i];
    bf16x4 o = {(__bf16)v.x, (__bf16)v.y, (__bf16)v.z, (__bf16)v.w};
    *(bf16x4*)&xb[i] = o;
    return;
  }
  bid -= 4096;
  if (bid < 4096) {
    const float* in;
    __bf16* out;
    int Cc, bx, by;
    if (bid < 3072) {
      in = W_attn; out = WaT; Cc = 3072; bx = bid % 96; by = bid / 96;
    } else {
      int b2 = bid - 3072;
      in = W_proj; out = WpT; Cc = 1024; bx = b2 % 32; by = b2 / 32;
    }
    const int R = 1024;
    int tx = t & 31, ty = t >> 5;
    int xcol = bx * 32 + tx;
    for (int r = ty; r < 32; r += 8)
      tile[r][tx] = in[(size_t)(by * 32 + r) * Cc + xcol];
    __syncthreads();
    int xo = by * 32 + tx;
    for (int r = ty; r < 32; r += 8)
      out[(size_t)(bx * 32 + r) * R + xo] = (__bf16)tile[tx][r];
    return;
  }
  bid -= 4096;
  int idx = bid * 256 + t;  // h*2048 + rp
  int h = idx >> 11, rp = idx & 2047;
  int bucket;
  if (rp < 16) {
    bucket = rp;
  } else {
    float v = (logf((float)rp * 0.0625f) / 2.0794415416798357f) * 16.0f;
    bucket = 16 + (int)v;
    if (bucket > 31) bucket = 31;
  }
  tbl[idx] = bt[bucket * 16 + h] * LOG2E;
}

// ------- QKV GEMM (round-11 proven form): 128x128 tile, 2-phase dbuf -------
// epilogue -> q*QSCALE [B,H,T,D], k [B,H,T,D], vT [B,H,D,T]
// 3 blocks/CU (32KB LDS): cross-block TLP fills the stage/barrier stalls —
// measured 44.6us / 570TF; the 256^2 8-phase port (1 block/CU, drain-0
// vmcnt) measured 65-67us. Do not regress to it without a derived-waits port.
__global__ __launch_bounds__(256) void gemm_qkv(
    const __bf16* __restrict__ A, const __bf16* __restrict__ BT,
    const float* __restrict__ bias,
    __bf16* __restrict__ qb, __bf16* __restrict__ kb, __bf16* __restrict__ vtb,
    int M, int N, int K) {
  __shared__ __align__(16) __bf16 lA[2][128 * 32];
  __shared__ __align__(16) __bf16 lB[2][128 * 32];
  const int t = threadIdx.x;
  const int w = t >> 6, lane = t & 63;
  const int m0 = blockIdx.x * 128, n0 = blockIdx.y * 128;
  const int wr = (w >> 1) * 64, wc = (w & 1) * 64;

  f32x4 acc[4][4] = {};

  const int rA = lane & 15;
  const int kk = (lane >> 4) * 8;

  auto STAGE = [&](int buf, int k0) {
#pragma unroll
    for (int r = 0; r < 2; ++r) {
      int c = r * 256 + t;
      int row = c >> 2, cc = c & 3;
      gload16(A + (size_t)(m0 + row) * K + k0 + cc * 8,
              &lA[buf][(r * 256 + w * 64) * 8]);
      gload16(BT + (size_t)(n0 + row) * K + k0 + cc * 8,
              &lB[buf][(r * 256 + w * 64) * 8]);
    }
  };

  STAGE(0, 0);
  int cur = 0;
  for (int k0 = 0; k0 < K; k0 += 32, cur ^= 1) {
    __syncthreads();                         // buf[cur] ready (vmcnt drained)
    if (k0 + 32 < K) STAGE(cur ^ 1, k0 + 32);  // prefetch flies under MFMA
    bf16x8 af[4], bfr[4];
#pragma unroll
    for (int i = 0; i < 4; ++i)
      af[i] = *(const bf16x8*)&lA[cur][(wr + i * 16 + rA) * 32 + kk];
#pragma unroll
    for (int j = 0; j < 4; ++j)
      bfr[j] = *(const bf16x8*)&lB[cur][(wc + j * 16 + rA) * 32 + kk];
#pragma unroll
    for (int i = 0; i < 4; ++i)
#pragma unroll
      for (int j = 0; j < 4; ++j)
        acc[i][j] = mfma16(af[i], bfr[j], acc[i][j]);
  }

  const int colb = n0 + wc + rA;
  const int rowb = m0 + wr + (lane >> 4) * 4;
#pragma unroll
  for (int j = 0; j < 4; ++j) {
    int n = colb + j * 16;
    float bv = bias[n];
#pragma unroll
    for (int i = 0; i < 4; ++i) {
#pragma unroll
      for (int e = 0; e < 4; ++e) {
        int m = rowb + i * 16 + e;
        float v = acc[i][j][e] + bv;
        int b = m >> 11, tt = m & 2047;
        int sec = n >> 10, nn = n & 1023;
        int h = nn >> 6, d = nn & 63;
        if (sec == 0)
          qb[(((size_t)(b * 16 + h)) * 2048 + tt) * 64 + d] = (__bf16)(v * QSCALE);
        else if (sec == 1)
          kb[(((size_t)(b * 16 + h)) * 2048 + tt) * 64 + d] = (__bf16)v;
        else
          vtb[(((size_t)(b * 16 + h)) * 64 + d) * 2048 + tt] = (__bf16)v;
      }
    }
  }
}

// ------- proj GEMM: 64x128 tile (2 blocks/CU for the small shape) -------
__global__ __launch_bounds__(256) void gemm_proj(
    const __bf16* __restrict__ A, const __bf16* __restrict__ BT,
    const float* __restrict__ bias, float* __restrict__ outF,
    int M, int N, int K) {
  __shared__ __align__(16) __bf16 lA[2][64 * 32];
  __shared__ __align__(16) __bf16 lB[2][128 * 32];
  const int t = threadIdx.x;
  const int w = t >> 6, lane = t & 63;
  const int m0 = blockIdx.x * 64, n0 = blockIdx.y * 128;
  const int wr = (w >> 1) * 32, wc = (w & 1) * 64;

  f32x4 acc[2][4] = {};

  const int rA = lane & 15;
  const int kk = (lane >> 4) * 8;

  auto STAGE = [&](int buf, int k0) {
    {
      int row = t >> 2, cc = t & 3;
      gload16(A + (size_t)(m0 + row) * K + k0 + cc * 8,
              &lA[buf][(w * 64) * 8]);
    }
#pragma unroll
    for (int r = 0; r < 2; ++r) {
      int c = r * 256 + t;
      int row = c >> 2, cc = c & 3;
      gload16(BT + (size_t)(n0 + row) * K + k0 + cc * 8,
              &lB[buf][(r * 256 + w * 64) * 8]);
    }
  };

  STAGE(0, 0);
  int cur = 0;
  for (int k0 = 0; k0 < K; k0 += 32, cur ^= 1) {
    __syncthreads();
    if (k0 + 32 < K) STAGE(cur ^ 1, k0 + 32);
    bf16x8 af[2], bfr[4];
#pragma unroll
    for (int i = 0; i < 2; ++i)
      af[i] = *(const bf16x8*)&lA[cur][(wr + i * 16 + rA) * 32 + kk];
#pragma unroll
    for (int j = 0; j < 4; ++j)
      bfr[j] = *(const bf16x8*)&lB[cur][(wc + j * 16 + rA) * 32 + kk];
#pragma unroll
    for (int i = 0; i < 2; ++i)
#pragma unroll
      for (int j = 0; j < 4; ++j)
        acc[i][j] = mfma16(af[i], bfr[j], acc[i][j]);
  }

  const int colb = n0 + wc + rA;
  const int rowb = m0 + wr + (lane >> 4) * 4;
#pragma unroll
  for (int j = 0; j < 4; ++j) {
    int n = colb + j * 16;
    float bv = bias[n];
#pragma unroll
    for (int i = 0; i < 2; ++i) {
#pragma unroll
      for (int e = 0; e < 4; ++e) {
        int m = rowb + i * 16 + e;
        outF[(size_t)m * N + n] = acc[i][j][e] + bv;
      }
    }
  }
}

// ------- flash attention: 32x32 MFMA, in-register P, key-split waves ---------
__global__ __launch_bounds__(256) void attn_k(
    const __bf16* __restrict__ q, const __bf16* __restrict__ k,
    const __bf16* __restrict__ vt, const float* __restrict__ tbl,
    __bf16* __restrict__ y) {
  // carve: lK[2] @0 (2x8KB) | lV[2] @16K (2x8KB) | lb[2] @32K (2x192 f32)
  __shared__ __align__(16) char smem[2 * 8192 + 2 * 8192 + 2 * 768];
  float* lbuf = (float*)(smem + 32768);

  const int t = threadIdx.x, w = t >> 6, lane = t & 63;
  const int bh = blockIdx.x, b = bh >> 4, h = bh & 15;
  const int qt64 = 31 - blockIdx.y;               // longest blocks first
  const int qs = w >> 1, ks = w & 1;
  const int ncol = lane & 31, hi = lane >> 5;
  const int swl = ncol & 7;                       // row&7 for all frag rows

  const __bf16* qp = q + (size_t)bh * 2048 * 64;
  const __bf16* kp = k + (size_t)bh * 2048 * 64;
  const __bf16* vp = vt + (size_t)bh * 64 * 2048;
  const float* tb = tbl + h * 2048;
  const float bconst = tb[2047] - FIXMAX;  // bucket-31 bias, fixed shift folded

  // Q B-frags: lane holds Q[qt64*64 + qs*32 + ncol][dc*16 + hi*8 + j]
  bf16x8 qf[4];
  {
    const __bf16* qr = qp + (size_t)(qt64 * 64 + qs * 32 + ncol) * 64 + hi * 8;
#pragma unroll
    for (int dc = 0; dc < 4; ++dc) qf[dc] = *(const bf16x8*)(qr + dc * 16);
  }

  f32x16 O0 = {}, O1 = {};
  float lsum = 0.f;
  const int ibase = 95 + 32 * (qs - ks) - 4 * hi + ncol;  // lb index base

  auto STAGE = [&](int buf, int jt) {
#pragma unroll
    for (int r = 0; r < 2; ++r) {
      int c = r * 256 + t;
      int row = c >> 3, cc = c & 7;
      int sc = cc ^ (row & 7);        // pre-swizzled source chunk
      gload16(kp + (size_t)(jt * 64 + row) * 64 + sc * 8,
              smem + buf * 8192 + (r * 256 + w * 64) * 16);
      gload16(vp + (size_t)row * 2048 + jt * 64 + sc * 8,
              smem + 16384 + buf * 8192 + (r * 256 + w * 64) * 16);
    }
    int dtj = qt64 - jt;
    if (dtj < 3 && t < 192) {         // bias window only near the diagonal
      int rb = dtj * 64 - 95 + t;
      lbuf[buf * 192 + t] = tb[rb < 0 ? 0 : rb] - FIXMAX;
    }
  };

  STAGE(0, 0);
  int cur = 0;
  for (int jt = 0; jt <= qt64; ++jt, cur ^= 1) {
    const int dt = qt64 - jt;
    const int rel = 2 * dt + qs - ks;
    __syncthreads();                        // buf[cur] ready (vmcnt drained)
    if (jt < qt64) STAGE(cur ^ 1, jt + 1);  // prefetch flies under compute
    if (rel < 0) continue;                  // wave-uniform: block fully masked

    const char* Kc = smem + cur * 8192;
    const char* Vc = smem + 16384 + cur * 8192;
    const float* lbc = lbuf + cur * 192;

    // C-init = bias - FIXMAX (and -1e30 on masked diagonal elements)
    f32x16 s;
    if (rel >= 5) {
#pragma unroll
      for (int r = 0; r < 16; ++r) s[r] = bconst;
    } else {
#pragma unroll
      for (int r = 0; r < 16; ++r) {
        int cr8 = (r & 3) + 8 * (r >> 2);       // crow without hi term
        float v = lbc[ibase - cr8];
        if (rel == 0 && ncol < cr8 + 4 * hi) v = -1e30f;
        s[r] = v;
      }
    }
    // S^T += K Q^T : A-frag K[key=ks*32+ncol][dc*16 + hi*8..], B-frag Q
    const char* Kb = Kc + (ks * 32 + ncol) * 128;
#pragma unroll
    for (int dc = 0; dc < 4; ++dc) {
      bf16x8 kf = *(const bf16x8*)(Kb + (((dc * 2 + hi) ^ swl) << 4));
      s = mfma32(kf, qf[dc], s);
    }
    // P = exp2(S); pack to PV A-frags in-register (no LDS bounce)
    float p[16];
#pragma unroll
    for (int r = 0; r < 16; ++r) {
      p[r] = exp2a(s[r]);
      lsum += p[r];
    }
#pragma unroll
    for (int s16 = 0; s16 < 2; ++s16) {
      unsigned we0 = cvtpk(p[8 * s16 + 0], p[8 * s16 + 1]);
      unsigned we1 = cvtpk(p[8 * s16 + 2], p[8 * s16 + 3]);
      unsigned wo0 = cvtpk(p[8 * s16 + 4], p[8 * s16 + 5]);
      unsigned wo1 = cvtpk(p[8 * s16 + 6], p[8 * s16 + 7]);
      u32x2 r0 = __builtin_amdgcn_permlane32_swap(we0, wo0, false, false);
      u32x2 r1 = __builtin_amdgcn_permlane32_swap(we1, wo1, false, false);
      u32x4 aw = {r0[0], r1[0], r0[1], r1[1]};
      bf16x8 af = __builtin_bit_cast(bf16x8, aw);
      // O += P V : B-frag V[key=(ks*2+s16)*16 + hi*8..][db*32+ncol]
#pragma unroll
      for (int db = 0; db < 2; ++db) {
        const char* Vb = Vc + (db * 32 + ncol) * 128;
        bf16x8 vf = *(const bf16x8*)(Vb +
            ((((ks * 2 + s16) * 2 + hi) ^ swl) << 4));
        if (db == 0) O0 = mfma32(af, vf, O0);
        else         O1 = mfma32(af, vf, O1);
      }
    }
  }

  // combine key-split partials: ks=1 waves export O/lsum via LDS, ks=0 add
  lsum += __shfl_xor(lsum, 32);
  __syncthreads();                    // all K/V reads done; smem reusable
  float* ls = (float*)(smem + 32768); // 512B lsum scratch (lb dead now)
  if (ks) {
    char* dst = smem + qs * 8192 + lane * 128;
#pragma unroll
    for (int c = 0; c < 4; ++c) {
      f32x4 v0 = {O0[4 * c], O0[4 * c + 1], O0[4 * c + 2], O0[4 * c + 3]};
      *(f32x4*)(dst + ((c ^ swl) << 4)) = v0;
      f32x4 v1 = {O1[4 * c], O1[4 * c + 1], O1[4 * c + 2], O1[4 * c + 3]};
      *(f32x4*)(dst + (((c + 4) ^ swl) << 4)) = v1;
    }
    ls[qs * 64 + lane] = lsum;
  }
  __syncthreads();
  if (!ks) {
    lsum += ls[qs * 64 + lane];
    const char* src = smem + qs * 8192 + lane * 128;
#pragma unroll
    for (int c = 0; c < 4; ++c) {
      f32x4 v0 = *(const f32x4*)(src + ((c ^ swl) << 4));
      f32x4 v1 = *(const f32x4*)(src + (((c + 4) ^ swl) << 4));
#pragma unroll
      for (int e = 0; e < 4; ++e) {
        O0[4 * c + e] += v0[e];
        O1[4 * c + e] += v1[e];
      }
    }
    // epilogue: lanes l and l^32 held complementary key-halves (combined)
    float rinv = 1.0f / lsum;         // for own qrow = ncol
#pragma unroll
    for (int r = 0; r < 16; ++r) {
      int cr = (r & 3) + 8 * (r >> 2) + 4 * hi;   // output qrow (C/D layout)
      float ri = __shfl(rinv, cr);                // lane cr owns qrow cr
      int row = qt64 * 64 + qs * 32 + cr;
      size_t base = ((size_t)(b * 2048 + row)) * 1024 + h * 64 + ncol;
      y[base]      = (__bf16)(O0[r] * ri);
      y[base + 32] = (__bf16)(O1[r] * ri);
    }
  }
}

// ---------------- launch ----------------

extern "C" void kernel_launch(void* const* d_in, const int* in_sizes, int n_in,
                              void* d_out, int out_size, void* d_ws, size_t ws_size,
                              hipStream_t stream) {
  const float* x = (const float*)d_in[0];
  const float* W_attn = (const float*)d_in[1];
  const float* b_attn = (const float*)d_in[2];
  const float* W_proj = (const float*)d_in[3];
  const float* b_proj = (const float*)d_in[4];
  const float* bias_table = (const float*)d_in[5];
  float* out = (float*)d_out;

  char* ws = (char*)d_ws;
  __bf16* xb   = (__bf16*)(ws + 0);          // 4096x1024           8 MB
  __bf16* WaT  = (__bf16*)(ws + 8388608);    // 3072x1024           6 MB
  __bf16* WpT  = (__bf16*)(ws + 14680064);   // 1024x1024           2 MB
  __bf16* qb   = (__bf16*)(ws + 16777216);   // [B,H,T,D]           8 MB
  __bf16* kb   = (__bf16*)(ws + 25165824);   // [B,H,T,D]           8 MB
  __bf16* vtb  = (__bf16*)(ws + 33554432);   // [B,H,D,T]           8 MB
  __bf16* yb   = (__bf16*)(ws + 41943040);   // [B,T,C]             8 MB
  float*  tbl  = (float*)(ws + 50331648);    // [H,T] bias*log2e  128 KB

  prep_k<<<8320, 256, 0, stream>>>(x, W_attn, W_proj, bias_table,
                                   xb, WaT, WpT, tbl);
  gemm_qkv<<<dim3(32, 24), 256, 0, stream>>>(xb, WaT, b_attn,
                                             qb, kb, vtb, 4096, 3072, 1024);
  attn_k<<<dim3(32, 32), 256, 0, stream>>>(qb, kb, vtb, tbl, yb);
  gemm_proj<<<dim3(64, 8), 256, 0, stream>>>(yb, WpT, b_proj, out,
                                             4096, 1024, 1024);
}

// Round 17
// 109.640 us; speedup vs baseline: 1.2159x; 1.0009x over previous
//
#include <hip/hip_runtime.h>
#include <hip/hip_bf16.h>
#include <math.h>

typedef __attribute__((ext_vector_type(4))) float f32x4;
typedef __attribute__((ext_vector_type(16))) float f32x16;
typedef __attribute__((ext_vector_type(8))) __bf16 bf16x8;
typedef __attribute__((ext_vector_type(4))) __bf16 bf16x4;
typedef __attribute__((ext_vector_type(4))) unsigned int u32x4;
typedef __attribute__((ext_vector_type(2))) unsigned int u32x2;

#define DEVI __device__ __forceinline__

DEVI f32x4 mfma16(bf16x8 a, bf16x8 b, f32x4 c) {
  return __builtin_amdgcn_mfma_f32_16x16x32_bf16(a, b, c, 0, 0, 0);
}
DEVI f32x16 mfma32(bf16x8 a, bf16x8 b, f32x16 c) {
  return __builtin_amdgcn_mfma_f32_32x32x16_bf16(a, b, c, 0, 0, 0);
}

// async global->LDS, 16B per lane; LDS dest = wave-uniform base + lane*16
DEVI void gload16(const void* g, void* l) {
  __builtin_amdgcn_global_load_lds(
      (const __attribute__((address_space(1))) void*)g,
      (__attribute__((address_space(3))) void*)l, 16, 0, 0);
}

DEVI float exp2a(float x) {  // single v_exp_f32 (exp2); inputs are log2-domain
  float r;
  asm("v_exp_f32 %0, %1" : "=v"(r) : "v"(x));
  return r;
}
DEVI unsigned cvtpk(float lo, float hi) {  // u32 = {bf16(lo), bf16(hi)}
  unsigned r;
  asm("v_cvt_pk_bf16_f32 %0, %1, %2" : "=v"(r) : "v"(lo), "v"(hi));
  return r;
}

#define LOG2E 1.4426950408889634f
#define QSCALE 0.18033688011110793f  /* 0.125 * log2(e) */
#define FIXMAX 8.0f  /* fixed softmax shift: S<<8 always; ratio O/lsum exact */

// ---------------- fused prep: x->bf16, W transposes, bias table ----------------
__global__ __launch_bounds__(256) void prep_k(
    const float* __restrict__ x, const float* __restrict__ W_attn,
    const float* __restrict__ W_proj, const float* __restrict__ bt,
    __bf16* __restrict__ xb, __bf16* __restrict__ WaT,
    __bf16* __restrict__ WpT, float* __restrict__ tbl) {
  __shared__ float tile[32][33];
  int bid = blockIdx.x;
  const int t = threadIdx.x;
  if (bid < 4096) {
    int i = (bid * 256 + t) * 4;
    float4 v = *(const float4*)&x[i];
    bf16x4 o = {(__bf16)v.x, (__bf16)v.y, (__bf16)v.z, (__bf16)v.w};
    *(bf16x4*)&xb[i] = o;
    return;
  }
  bid -= 4096;
  if (bid < 4096) {
    const float* in;
    __bf16* out;
    int Cc, bx, by;
    if (bid < 3072) {
      in = W_attn; out = WaT; Cc = 3072; bx = bid % 96; by = bid / 96;
    } else {
      int b2 = bid - 3072;
      in = W_proj; out = WpT; Cc = 1024; bx = b2 % 32; by = b2 / 32;
    }
    const int R = 1024;
    int tx = t & 31, ty = t >> 5;
    int xcol = bx * 32 + tx;
    for (int r = ty; r < 32; r += 8)
      tile[r][tx] = in[(size_t)(by * 32 + r) * Cc + xcol];
    __syncthreads();
    int xo = by * 32 + tx;
    for (int r = ty; r < 32; r += 8)
      out[(size_t)(bx * 32 + r) * R + xo] = (__bf16)tile[tx][r];
    return;
  }
  bid -= 4096;
  int idx = bid * 256 + t;  // h*2048 + rp
  int h = idx >> 11, rp = idx & 2047;
  int bucket;
  if (rp < 16) {
    bucket = rp;
  } else {
    float v = (logf((float)rp * 0.0625f) / 2.0794415416798357f) * 16.0f;
    bucket = 16 + (int)v;
    if (bucket > 31) bucket = 31;
  }
  tbl[idx] = bt[bucket * 16 + h] * LOG2E;
}

// ------- QKV GEMM (round-11 proven form): 128x128 tile, 2-phase dbuf -------
// 3 blocks/CU (32KB LDS): cross-block TLP fills the stage/barrier stalls —
// measured 44.6us / 570TF; 256^2 8-phase port (1 block/CU) measured 65-67us.
__global__ __launch_bounds__(256) void gemm_qkv(
    const __bf16* __restrict__ A, const __bf16* __restrict__ BT,
    const float* __restrict__ bias,
    __bf16* __restrict__ qb, __bf16* __restrict__ kb, __bf16* __restrict__ vtb,
    int M, int N, int K) {
  __shared__ __align__(16) __bf16 lA[2][128 * 32];
  __shared__ __align__(16) __bf16 lB[2][128 * 32];
  const int t = threadIdx.x;
  const int w = t >> 6, lane = t & 63;
  const int m0 = blockIdx.x * 128, n0 = blockIdx.y * 128;
  const int wr = (w >> 1) * 64, wc = (w & 1) * 64;

  f32x4 acc[4][4] = {};

  const int rA = lane & 15;
  const int kk = (lane >> 4) * 8;

  auto STAGE = [&](int buf, int k0) {
#pragma unroll
    for (int r = 0; r < 2; ++r) {
      int c = r * 256 + t;
      int row = c >> 2, cc = c & 3;
      gload16(A + (size_t)(m0 + row) * K + k0 + cc * 8,
              &lA[buf][(r * 256 + w * 64) * 8]);
      gload16(BT + (size_t)(n0 + row) * K + k0 + cc * 8,
              &lB[buf][(r * 256 + w * 64) * 8]);
    }
  };

  STAGE(0, 0);
  int cur = 0;
  for (int k0 = 0; k0 < K; k0 += 32, cur ^= 1) {
    __syncthreads();                         // buf[cur] ready (vmcnt drained)
    if (k0 + 32 < K) STAGE(cur ^ 1, k0 + 32);  // prefetch flies under MFMA
    bf16x8 af[4], bfr[4];
#pragma unroll
    for (int i = 0; i < 4; ++i)
      af[i] = *(const bf16x8*)&lA[cur][(wr + i * 16 + rA) * 32 + kk];
#pragma unroll
    for (int j = 0; j < 4; ++j)
      bfr[j] = *(const bf16x8*)&lB[cur][(wc + j * 16 + rA) * 32 + kk];
#pragma unroll
    for (int i = 0; i < 4; ++i)
#pragma unroll
      for (int j = 0; j < 4; ++j)
        acc[i][j] = mfma16(af[i], bfr[j], acc[i][j]);
  }

  const int colb = n0 + wc + rA;
  const int rowb = m0 + wr + (lane >> 4) * 4;
#pragma unroll
  for (int j = 0; j < 4; ++j) {
    int n = colb + j * 16;
    float bv = bias[n];
#pragma unroll
    for (int i = 0; i < 4; ++i) {
#pragma unroll
      for (int e = 0; e < 4; ++e) {
        int m = rowb + i * 16 + e;
        float v = acc[i][j][e] + bv;
        int b = m >> 11, tt = m & 2047;
        int sec = n >> 10, nn = n & 1023;
        int h = nn >> 6, d = nn & 63;
        if (sec == 0)
          qb[(((size_t)(b * 16 + h)) * 2048 + tt) * 64 + d] = (__bf16)(v * QSCALE);
        else if (sec == 1)
          kb[(((size_t)(b * 16 + h)) * 2048 + tt) * 64 + d] = (__bf16)v;
        else
          vtb[(((size_t)(b * 16 + h)) * 64 + d) * 2048 + tt] = (__bf16)v;
      }
    }
  }
}

// ------- proj GEMM: 64x128 tile (2 blocks/CU for the small shape) -------
__global__ __launch_bounds__(256) void gemm_proj(
    const __bf16* __restrict__ A, const __bf16* __restrict__ BT,
    const float* __restrict__ bias, float* __restrict__ outF,
    int M, int N, int K) {
  __shared__ __align__(16) __bf16 lA[2][64 * 32];
  __shared__ __align__(16) __bf16 lB[2][128 * 32];
  const int t = threadIdx.x;
  const int w = t >> 6, lane = t & 63;
  const int m0 = blockIdx.x * 64, n0 = blockIdx.y * 128;
  const int wr = (w >> 1) * 32, wc = (w & 1) * 64;

  f32x4 acc[2][4] = {};

  const int rA = lane & 15;
  const int kk = (lane >> 4) * 8;

  auto STAGE = [&](int buf, int k0) {
    {
      int row = t >> 2, cc = t & 3;
      gload16(A + (size_t)(m0 + row) * K + k0 + cc * 8,
              &lA[buf][(w * 64) * 8]);
    }
#pragma unroll
    for (int r = 0; r < 2; ++r) {
      int c = r * 256 + t;
      int row = c >> 2, cc = c & 3;
      gload16(BT + (size_t)(n0 + row) * K + k0 + cc * 8,
              &lB[buf][(r * 256 + w * 64) * 8]);
    }
  };

  STAGE(0, 0);
  int cur = 0;
  for (int k0 = 0; k0 < K; k0 += 32, cur ^= 1) {
    __syncthreads();
    if (k0 + 32 < K) STAGE(cur ^ 1, k0 + 32);
    bf16x8 af[2], bfr[4];
#pragma unroll
    for (int i = 0; i < 2; ++i)
      af[i] = *(const bf16x8*)&lA[cur][(wr + i * 16 + rA) * 32 + kk];
#pragma unroll
    for (int j = 0; j < 4; ++j)
      bfr[j] = *(const bf16x8*)&lB[cur][(wc + j * 16 + rA) * 32 + kk];
#pragma unroll
    for (int i = 0; i < 2; ++i)
#pragma unroll
      for (int j = 0; j < 4; ++j)
        acc[i][j] = mfma16(af[i], bfr[j], acc[i][j]);
  }

  const int colb = n0 + wc + rA;
  const int rowb = m0 + wr + (lane >> 4) * 4;
#pragma unroll
  for (int j = 0; j < 4; ++j) {
    int n = colb + j * 16;
    float bv = bias[n];
#pragma unroll
    for (int i = 0; i < 2; ++i) {
#pragma unroll
      for (int e = 0; e < 4; ++e) {
        int m = rowb + i * 16 + e;
        outF[(size_t)m * N + n] = acc[i][j][e] + bv;
      }
    }
  }
}

// ------- flash attention: 32x32 MFMA, in-register P, key-split waves ---------
// grid.x = b*16+h (32), grid.y -> qt64 = 31 - blockIdx.y; 256 thr = 4 waves.
// Wave (qs=w>>1, ks=w&1): q-rows qt64*64 + qs*32 .. +32, key-half ks of each
// 64-key tile. K/V staged block-wide (double-buffered); fixed-max softmax
// makes the ks-combine additive: one LDS exchange of partial O/lsum at end.
// rel32 = 2*dt + qs - ks: <0 skip, ==0 diag-mask, >=5 saturated bias.
__global__ __launch_bounds__(256) void attn_k(
    const __bf16* __restrict__ q, const __bf16* __restrict__ k,
    const __bf16* __restrict__ vt, const float* __restrict__ tbl,
    __bf16* __restrict__ y) {
  // carve: lK[2] @0 (2x8KB) | lV[2] @16K (2x8KB) | lb[2] @32K (2x192 f32)
  __shared__ __align__(16) char smem[2 * 8192 + 2 * 8192 + 2 * 768];
  float* lbuf = (float*)(smem + 32768);

  const int t = threadIdx.x, w = t >> 6, lane = t & 63;
  const int bh = blockIdx.x, b = bh >> 4, h = bh & 15;
  const int qt64 = 31 - blockIdx.y;               // longest blocks first
  const int qs = w >> 1, ks = w & 1;
  const int ncol = lane & 31, hi = lane >> 5;
  const int swl = ncol & 7;                       // row&7 for all frag rows

  const __bf16* qp = q + (size_t)bh * 2048 * 64;
  const __bf16* kp = k + (size_t)bh * 2048 * 64;
  const __bf16* vp = vt + (size_t)bh * 64 * 2048;
  const float* tb = tbl + h * 2048;
  const float bconst = tb[2047] - FIXMAX;  // bucket-31 bias, fixed shift folded

  // Q B-frags: lane holds Q[qt64*64 + qs*32 + ncol][dc*16 + hi*8 + j]
  bf16x8 qf[4];
  {
    const __bf16* qr = qp + (size_t)(qt64 * 64 + qs * 32 + ncol) * 64 + hi * 8;
#pragma unroll
    for (int dc = 0; dc < 4; ++dc) qf[dc] = *(const bf16x8*)(qr + dc * 16);
  }

  f32x16 O0 = {}, O1 = {};
  float lsum = 0.f;
  const int ibase = 95 + 32 * (qs - ks) - 4 * hi + ncol;  // lb index base

  auto STAGE = [&](int buf, int jt) {
#pragma unroll
    for (int r = 0; r < 2; ++r) {
      int c = r * 256 + t;
      int row = c >> 3, cc = c & 7;
      int sc = cc ^ (row & 7);        // pre-swizzled source chunk
      gload16(kp + (size_t)(jt * 64 + row) * 64 + sc * 8,
              smem + buf * 8192 + (r * 256 + w * 64) * 16);
      gload16(vp + (size_t)row * 2048 + jt * 64 + sc * 8,
              smem + 16384 + buf * 8192 + (r * 256 + w * 64) * 16);
    }
    int dtj = qt64 - jt;
    if (dtj < 3 && t < 192) {         // bias window only near the diagonal
      int rb = dtj * 64 - 95 + t;
      lbuf[buf * 192 + t] = tb[rb < 0 ? 0 : rb] - FIXMAX;
    }
  };

  STAGE(0, 0);
  int cur = 0;
  for (int jt = 0; jt <= qt64; ++jt, cur ^= 1) {
    const int dt = qt64 - jt;
    const int rel = 2 * dt + qs - ks;
    __syncthreads();                        // buf[cur] ready (vmcnt drained)
    if (jt < qt64) STAGE(cur ^ 1, jt + 1);  // prefetch flies under compute
    if (rel < 0) continue;                  // wave-uniform: block fully masked

    const char* Kc = smem + cur * 8192;
    const char* Vc = smem + 16384 + cur * 8192;
    const float* lbc = lbuf + cur * 192;

    // C-init = bias - FIXMAX (and -1e30 on masked diagonal elements)
    f32x16 s;
    if (rel >= 5) {
#pragma unroll
      for (int r = 0; r < 16; ++r) s[r] = bconst;
    } else {
#pragma unroll
      for (int r = 0; r < 16; ++r) {
        int cr8 = (r & 3) + 8 * (r >> 2);       // crow without hi term
        float v = lbc[ibase - cr8];
        if (rel == 0 && ncol < cr8 + 4 * hi) v = -1e30f;
        s[r] = v;
      }
    }
    // S^T += K Q^T : A-frag K[key=ks*32+ncol][dc*16 + hi*8..], B-frag Q
    const char* Kb = Kc + (ks * 32 + ncol) * 128;
#pragma unroll
    for (int dc = 0; dc < 4; ++dc) {
      bf16x8 kf = *(const bf16x8*)(Kb + (((dc * 2 + hi) ^ swl) << 4));
      s = mfma32(kf, qf[dc], s);
    }
    // P = exp2(S); pack to PV A-frags in-register (no LDS bounce)
    float p[16];
#pragma unroll
    for (int r = 0; r < 16; ++r) {
      p[r] = exp2a(s[r]);
      lsum += p[r];
    }
#pragma unroll
    for (int s16 = 0; s16 < 2; ++s16) {
      unsigned we0 = cvtpk(p[8 * s16 + 0], p[8 * s16 + 1]);
      unsigned we1 = cvtpk(p[8 * s16 + 2], p[8 * s16 + 3]);
      unsigned wo0 = cvtpk(p[8 * s16 + 4], p[8 * s16 + 5]);
      unsigned wo1 = cvtpk(p[8 * s16 + 6], p[8 * s16 + 7]);
      u32x2 r0 = __builtin_amdgcn_permlane32_swap(we0, wo0, false, false);
      u32x2 r1 = __builtin_amdgcn_permlane32_swap(we1, wo1, false, false);
      u32x4 aw = {r0[0], r1[0], r0[1], r1[1]};
      bf16x8 af = __builtin_bit_cast(bf16x8, aw);
      // O += P V : B-frag V[key=(ks*2+s16)*16 + hi*8..][db*32+ncol]
#pragma unroll
      for (int db = 0; db < 2; ++db) {
        const char* Vb = Vc + (db * 32 + ncol) * 128;
        bf16x8 vf = *(const bf16x8*)(Vb +
            ((((ks * 2 + s16) * 2 + hi) ^ swl) << 4));
        if (db == 0) O0 = mfma32(af, vf, O0);
        else         O1 = mfma32(af, vf, O1);
      }
    }
  }

  // combine key-split partials: ks=1 waves export O/lsum via LDS, ks=0 add
  lsum += __shfl_xor(lsum, 32);
  __syncthreads();                    // all K/V reads done; smem reusable
  float* ls = (float*)(smem + 32768); // 512B lsum scratch (lb dead now)
  if (ks) {
    char* dst = smem + qs * 8192 + lane * 128;
#pragma unroll
    for (int c = 0; c < 4; ++c) {
      f32x4 v0 = {O0[4 * c], O0[4 * c + 1], O0[4 * c + 2], O0[4 * c + 3]};
      *(f32x4*)(dst + ((c ^ swl) << 4)) = v0;
      f32x4 v1 = {O1[4 * c], O1[4 * c + 1], O1[4 * c + 2], O1[4 * c + 3]};
      *(f32x4*)(dst + (((c + 4) ^ swl) << 4)) = v1;
    }
    ls[qs * 64 + lane] = lsum;
  }
  __syncthreads();
  if (!ks) {
    lsum += ls[qs * 64 + lane];
    const char* src = smem + qs * 8192 + lane * 128;
#pragma unroll
    for (int c = 0; c < 4; ++c) {
      f32x4 v0 = *(const f32x4*)(src + ((c ^ swl) << 4));
      f32x4 v1 = *(const f32x4*)(src + (((c + 4) ^ swl) << 4));
#pragma unroll
      for (int e = 0; e < 4; ++e) {
        O0[4 * c + e] += v0[e];
        O1[4 * c + e] += v1[e];
      }
    }
    // epilogue: lanes l and l^32 held complementary key-halves (combined)
    float rinv = 1.0f / lsum;         // for own qrow = ncol
#pragma unroll
    for (int r = 0; r < 16; ++r) {
      int cr = (r & 3) + 8 * (r >> 2) + 4 * hi;   // output qrow (C/D layout)
      float ri = __shfl(rinv, cr);                // lane cr owns qrow cr
      int row = qt64 * 64 + qs * 32 + cr;
      size_t base = ((size_t)(b * 2048 + row)) * 1024 + h * 64 + ncol;
      y[base]      = (__bf16)(O0[r] * ri);
      y[base + 32] = (__bf16)(O1[r] * ri);
    }
  }
}

// ---------------- launch ----------------

extern "C" void kernel_launch(void* const* d_in, const int* in_sizes, int n_in,
                              void* d_out, int out_size, void* d_ws, size_t ws_size,
                              hipStream_t stream) {
  const float* x = (const float*)d_in[0];
  const float* W_attn = (const float*)d_in[1];
  const float* b_attn = (const float*)d_in[2];
  const float* W_proj = (const float*)d_in[3];
  const float* b_proj = (const float*)d_in[4];
  const float* bias_table = (const float*)d_in[5];
  float* out = (float*)d_out;

  char* ws = (char*)d_ws;
  __bf16* xb   = (__bf16*)(ws + 0);          // 4096x1024           8 MB
  __bf16* WaT  = (__bf16*)(ws + 8388608);    // 3072x1024           6 MB
  __bf16* WpT  = (__bf16*)(ws + 14680064);   // 1024x1024           2 MB
  __bf16* qb   = (__bf16*)(ws + 16777216);   // [B,H,T,D]           8 MB
  __bf16* kb   = (__bf16*)(ws + 25165824);   // [B,H,T,D]           8 MB
  __bf16* vtb  = (__bf16*)(ws + 33554432);   // [B,H,D,T]           8 MB
  __bf16* yb   = (__bf16*)(ws + 41943040);   // [B,T,C]             8 MB
  float*  tbl  = (float*)(ws + 50331648);    // [H,T] bias*log2e  128 KB

  prep_k<<<8320, 256, 0, stream>>>(x, W_attn, W_proj, bias_table,
                                   xb, WaT, WpT, tbl);
  gemm_qkv<<<dim3(32, 24), 256, 0, stream>>>(xb, WaT, b_attn,
                                             qb, kb, vtb, 4096, 3072, 1024);
  attn_k<<<dim3(32, 32), 256, 0, stream>>>(qb, kb, vtb, tbl, yb);
  gemm_proj<<<dim3(64, 8), 256, 0, stream>>>(yb, WpT, b_proj, out,
                                             4096, 1024, 1024);
}